// Round 13
// baseline (639.649 us; speedup 1.0000x reference)
//
#include <hip/hip_runtime.h>
#include <hip/hip_bf16.h>
#include <math.h>

#define D_MODEL 1024
#define D_FF    4096
#define NEXP    8
#define NTOK    4096
#define NROUTED 8192
#define MAXJOBS 40

typedef __attribute__((ext_vector_type(8))) short bf16x8;
typedef __attribute__((ext_vector_type(4))) float f32x4;
typedef __attribute__((ext_vector_type(4))) unsigned short us4;

// ---- workspace byte offsets ----
#define WS_CNT   0                         // int[8]
#define WS_CNT2  64                        // int[8]
#define WS_OFF   128                       // int[9]
#define WS_JOBS  192                       // int[1+MAXJOBS]
#define WS_TI    512                       // int[NTOK*2]
#define WS_TW    (WS_TI + NTOK*2*4)        // float[NTOK*2]
#define WS_TOK   (WS_TW + NTOK*2*4)        // int[NROUTED]
#define WS_GWT   (WS_TOK + NROUTED*4)      // float[NROUTED]
#define WS_XG    (((WS_GWT + NROUTED*4) + 255) & ~255)       // bf16[NROUTED][1024]  (16 MB)
#define WS_H     (WS_XG + (size_t)NROUTED*D_MODEL*2)         // bf16[NROUTED][4096]  (64 MB)
#define WS_WT    (WS_H + (size_t)NROUTED*D_FF*2)             // bf16[E][F][K] shared (64 MB)
// total ~144 MB

__device__ __forceinline__ unsigned short f2bf(float f){
  union { float f; unsigned u; } a; a.f = f;
  unsigned u = a.u;
  u = u + 0x7FFF + ((u >> 16) & 1);   // RNE
  return (unsigned short)(u >> 16);
}

__device__ __forceinline__ void gload_lds16(const void* g, void* l){
  __builtin_amdgcn_global_load_lds((const __attribute__((address_space(1))) void*)g,
                                   (__attribute__((address_space(3))) void*)l, 16, 0, 0);
}

// ---------------- gating ----------------
__global__ void moe_gate_kernel(const float* __restrict__ x, const float* __restrict__ gw,
                                int* cnt, int* __restrict__ ti, float* __restrict__ tw){
  int n = blockIdx.x*4 + (threadIdx.x >> 6);
  int lane = threadIdx.x & 63;
  const float* xr = x + (size_t)n * D_MODEL;
  float acc[NEXP];
  #pragma unroll
  for (int e=0;e<NEXP;e++) acc[e] = 0.f;
  for (int d=lane; d<D_MODEL; d+=64){
    float xv = xr[d];
    #pragma unroll
    for (int e=0;e<NEXP;e++) acc[e] += xv * gw[d*NEXP + e];
  }
  #pragma unroll
  for (int e=0;e<NEXP;e++){
    #pragma unroll
    for (int o=32;o;o>>=1) acc[e] += __shfl_down(acc[e], o, 64);
  }
  if (lane == 0){
    int i0 = 0; float v0 = acc[0];
    #pragma unroll
    for (int e=1;e<NEXP;e++) if (acc[e] > v0){ v0 = acc[e]; i0 = e; }
    int i1 = -1; float v1 = -1e30f;
    #pragma unroll
    for (int e=0;e<NEXP;e++) if (e != i0 && acc[e] > v1){ v1 = acc[e]; i1 = e; }
    float p = expf(v1 - v0);
    float inv = 1.f / (1.f + p);
    ti[n*2] = i0; ti[n*2+1] = i1;
    tw[n*2] = inv; tw[n*2+1] = p * inv;
    atomicAdd(&cnt[i0], 1); atomicAdd(&cnt[i1], 1);
  }
}

// prefix sums + job list (job = one 256-row stripe of one expert)
__global__ void moe_prefix_kernel(const int* __restrict__ cnt, int* __restrict__ off,
                                  int* __restrict__ jobs){
  if (threadIdx.x == 0){
    int s = 0;
    for (int e=0;e<NEXP;e++){ off[e] = s; s += cnt[e]; }
    off[NEXP] = s;
    int idx = 0;
    for (int e=0;e<NEXP;e++){
      int ns = (cnt[e] + 255) >> 8;
      for (int q=0;q<ns;q++) jobs[1+idx++] = (e<<16) | q;
    }
    jobs[0] = idx;
  }
}

__global__ void moe_assign_kernel(const float* __restrict__ x, const int* __restrict__ ti,
                                  const float* __restrict__ tw, const int* __restrict__ off,
                                  int* cnt2, int* __restrict__ tok, float* __restrict__ gwt,
                                  unsigned short* __restrict__ Xg){
  __shared__ int ss[2];
  int n = blockIdx.x;
  if (threadIdx.x == 0){
    int i0 = ti[n*2], i1 = ti[n*2+1];
    int s0 = off[i0] + atomicAdd(&cnt2[i0], 1);
    int s1 = off[i1] + atomicAdd(&cnt2[i1], 1);
    tok[s0] = n; tok[s1] = n;
    gwt[s0] = tw[n*2]; gwt[s1] = tw[n*2+1];
    ss[0] = s0; ss[1] = s1;
  }
  __syncthreads();
  int s0 = ss[0], s1 = ss[1];
  int t = threadIdx.x;
  f32x4 v = *(const f32x4*)(x + (size_t)n * D_MODEL + t*4);
  us4 pk = { f2bf(v.x), f2bf(v.y), f2bf(v.z), f2bf(v.w) };
  // NT: written once, consumed by GEMM1 on other XCDs -> don't pollute L2
  __builtin_nontemporal_store(pk, (us4*)(Xg + (size_t)s0 * D_MODEL + t*4));
  __builtin_nontemporal_store(pk, (us4*)(Xg + (size_t)s1 * D_MODEL + t*4));
}

// ---------------- weight transpose + bf16 convert: W(E,K,F) f32 -> Wt(E,F,K) bf16 ----------------
__global__ __launch_bounds__(256) void transpose_bf16_kernel(
    const float* __restrict__ W, unsigned short* __restrict__ Wt, int K, int F){
  __shared__ float tile[64][65];
  int e = blockIdx.z;
  int f0 = blockIdx.x * 64, k0 = blockIdx.y * 64;
  const float* Wb = W + (size_t)e * K * F;
  unsigned short* Wtb = Wt + (size_t)e * F * K;
  int tid = threadIdx.x;
  #pragma unroll
  for (int i=0;i<4;i++){
    int idx = i*256 + tid;
    int r = idx >> 4, c4 = (idx & 15) * 4;
    f32x4 v = __builtin_nontemporal_load((const f32x4*)(Wb + (size_t)(k0 + r) * F + f0 + c4));
    tile[r][c4] = v.x; tile[r][c4+1] = v.y; tile[r][c4+2] = v.z; tile[r][c4+3] = v.w;
  }
  __syncthreads();
  #pragma unroll
  for (int i=0;i<4;i++){
    int idx = i*256 + tid;
    int f = idx >> 4, k4 = (idx & 15) * 4;
    us4 pk = { f2bf(tile[k4][f]), f2bf(tile[k4+1][f]), f2bf(tile[k4+2][f]), f2bf(tile[k4+3][f]) };
    __builtin_nontemporal_store(pk, (us4*)(Wtb + (size_t)(f0 + f) * K + k0 + k4));
  }
}

// ---------------- GEMM: 256x256 tile, BK=32, 8 waves (512 thr), wave-tile 128x64 ----------------
// Register-pipelined ring-3: frags(tile t+1) ds_read during tile t's phase; MFMA(t) has no
// dependence on the just-issued reads -> compiler counted-lgkmcnt overlaps reads & VMEM under MFMA.
// Counted vmcnt(4) + one s_barrier per K-tile. No lgkmcnt(0)/sched_barrier pinning.
// MODE 1: Xg@W1t^T -> gelu -> H(NT)   (K=1024, NT=32; grid.x = 16 col-tiles)
// MODE 2: H@W2t^T *g -> atomic out    (K=4096 split 2-way; grid.x=(kchunk<<2)|col; NT=64)
template<int MODE>
__global__ __launch_bounds__(512, 2) void moe_gemm_kernel(
    char* __restrict__ wsb, const unsigned short* __restrict__ Bt,
    const float* __restrict__ bias, float* __restrict__ out)
{
  const int* jobs = (const int*)(wsb + WS_JOBS);
  if ((int)blockIdx.y >= jobs[0]) return;
  const int jb = jobs[1 + blockIdx.y];
  const int e = jb >> 16;
  const int row0 = (jb & 0xffff) << 8;

  const int* off = (const int*)(wsb + WS_OFF);
  const int n0 = off[e];
  const int ne = off[e+1] - n0;

  constexpr int K  = (MODE==1) ? D_MODEL : D_FF;
  constexpr int NT = (MODE==1) ? 32 : 64;         // BK=32 K-tiles
  const int bx     = (MODE==1) ? blockIdx.x : (blockIdx.x & 3);
  const int kchunk = (MODE==1) ? 0 : (blockIdx.x >> 2);
  const int n_off  = bx * 256;
  const size_t kcb = (size_t)kchunk * 4096;       // byte offset of 2048-wide K-chunk

  const unsigned short* Ag  = (const unsigned short*)(wsb + (MODE==1 ? (size_t)WS_XG : (size_t)WS_H));
  const unsigned short* Bgt = Bt + (size_t)e * D_FF * D_MODEL;

  __shared__ __align__(16) char lds[3*32768];     // ring-3: [slot][ A 16KB | B 16KB ]

  const int tid = threadIdx.x, lane = tid & 63, w = tid >> 6;
  const int wr = w >> 2, wc = w & 3;              // 2x4 wave grid; wave tile 128 x 64

  // ---- staging: 4 x gload_lds16 per thread per K-tile (2 A-sweeps + 2 B-sweeps) ----
  const int rs = w*16 + (lane >> 2);              // 0..127 (sweep1 adds +128)
  const int qs = ((lane & 3) ^ ((rs >> 1) & 3)) << 4;   // pre-swizzled chunk (free: (r+128)>>1 same &3)
  int gr0 = row0 + rs;        if (gr0 >= ne) gr0 = ne - 1;
  int gr1 = row0 + 128 + rs;  if (gr1 >= ne) gr1 = ne - 1;
  const char* aSrc0 = (const char*)(Ag + (size_t)(n0 + gr0) * K) + kcb + qs;
  const char* aSrc1 = (const char*)(Ag + (size_t)(n0 + gr1) * K) + kcb + qs;
  const char* bSrc0 = (const char*)(Bgt + (size_t)(n_off + rs) * K) + kcb + qs;
  const char* bSrc1 = (const char*)(Bgt + (size_t)(n_off + 128 + rs) * K) + kcb + qs;
  const int dstOff = w*1024;                      // wave-uniform LDS dest base

  // ---- fragment read offsets (2-way bank = free; r11-verified swizzle) ----
  const int q0 = lane >> 4;
  int aoff[8], boff[4];
  #pragma unroll
  for (int mi=0; mi<8; mi++){
    int row = wr*128 + mi*16 + (lane & 15);
    aoff[mi] = row*64 + ((q0 ^ ((row>>1)&3)) << 4);
  }
  #pragma unroll
  for (int ni=0; ni<4; ni++){
    int col = wc*64 + ni*16 + (lane & 15);
    boff[ni] = 16384 + col*64 + ((q0 ^ ((col>>1)&3)) << 4);
  }

  f32x4 acc[8][4];
  #pragma unroll
  for (int i=0;i<8;i++)
    #pragma unroll
    for (int j=0;j<4;j++) acc[i][j] = (f32x4){0.f,0.f,0.f,0.f};

  #define STAGE(tt, ss) { \
    size_t kb = (size_t)(tt)*64; \
    char* d = lds + (ss)*32768; \
    gload_lds16(aSrc0 + kb, d + dstOff); \
    gload_lds16(aSrc1 + kb, d + 8192 + dstOff); \
    gload_lds16(bSrc0 + kb, d + 16384 + dstOff); \
    gload_lds16(bSrc1 + kb, d + 24576 + dstOff); }

  #define READ(A_, B_, base_) { \
    _Pragma("unroll") \
    for (int mi=0; mi<8; mi++) A_[mi] = *(const bf16x8*)((base_) + aoff[mi]); \
    _Pragma("unroll") \
    for (int ni=0; ni<4; ni++) B_[ni] = *(const bf16x8*)((base_) + boff[ni]); }

  #define MM(A_, B_) { \
    __builtin_amdgcn_s_setprio(1); \
    _Pragma("unroll") \
    for (int ni=0; ni<4; ni++) \
      _Pragma("unroll") \
      for (int mi=0; mi<8; mi++) \
        acc[mi][ni] = __builtin_amdgcn_mfma_f32_16x16x32_bf16(A_[mi], B_[ni], acc[mi][ni], 0, 0, 0); \
    __builtin_amdgcn_s_setprio(0); }

  bf16x8 aA[8], bA[4], aB[8], bB[4];

  // prologue: tiles 0,1 staged; tile 0 frags -> regs
  STAGE(0, 0);
  STAGE(1, 1);
  asm volatile("s_waitcnt vmcnt(4)" ::: "memory");
  __builtin_amdgcn_s_barrier();
  READ(aA, bA, lds);

  for (int t = 0; t < NT; t += 2){
    // ---- half 1: MFMA tile t, read frags(t+1) ----
    if (t + 2 < NT){
      STAGE(t + 2, (t + 2) % 3);
      asm volatile("s_waitcnt vmcnt(4)" ::: "memory");    // tile t+1 landed
    } else {
      asm volatile("s_waitcnt vmcnt(0)" ::: "memory");
    }
    __builtin_amdgcn_s_barrier();
    READ(aB, bB, lds + ((t + 1) % 3) * 32768);
    MM(aA, bA);
    // ---- half 2: MFMA tile t+1, read frags(t+2) ----
    if (t + 2 < NT){
      if (t + 3 < NT){
        STAGE(t + 3, (t + 3) % 3);
        asm volatile("s_waitcnt vmcnt(4)" ::: "memory");  // tile t+2 landed
      } else {
        asm volatile("s_waitcnt vmcnt(0)" ::: "memory");
      }
      __builtin_amdgcn_s_barrier();
      READ(aA, bA, lds + ((t + 2) % 3) * 32768);
    }
    MM(aB, bB);
  }
  #undef STAGE
  #undef READ
  #undef MM

  // ---- epilogue (wave tile 128 x 64) ----
  if (MODE == 1){
    const float* b1 = bias + (size_t)e * D_FF;
    unsigned short* H = (unsigned short*)(wsb + (size_t)WS_H);
    #pragma unroll
    for (int mi=0; mi<8; mi++){
      int rbase = wr*128 + mi*16 + ((lane>>4)<<2);
      #pragma unroll
      for (int rr=0;rr<4;rr++){
        int lrow = rbase + rr;
        if (row0 + lrow < ne){
          size_t hb = (size_t)(n0 + row0 + lrow) * D_FF;
          #pragma unroll
          for (int ni=0; ni<4; ni++){
            int gcol = n_off + wc*64 + ni*16 + (lane&15);
            float v = acc[mi][ni][rr] + b1[gcol];
            v = 0.5f * v * (1.f + erff(v * 0.70710678118654752f));
            __builtin_nontemporal_store(f2bf(v), H + hb + gcol);   // NT: consumed cross-XCD
          }
        }
      }
    }
  } else {
    const float* b2 = bias + (size_t)e * D_MODEL;
    const int* tok = (const int*)(wsb + WS_TOK);
    const float* gwt = (const float*)(wsb + WS_GWT);
    #pragma unroll
    for (int mi=0; mi<8; mi++){
      int rbase = wr*128 + mi*16 + ((lane>>4)<<2);
      #pragma unroll
      for (int rr=0;rr<4;rr++){
        int lrow = rbase + rr;
        if (row0 + lrow < ne){
          int slot = n0 + row0 + lrow;
          int tk = tok[slot];
          float g = gwt[slot];
          float* orow = out + (size_t)tk * D_MODEL;
          #pragma unroll
          for (int ni=0; ni<4; ni++){
            int gcol = n_off + wc*64 + ni*16 + (lane&15);
            float bb = (kchunk == 0) ? b2[gcol] : 0.f;
            atomicAdd(orow + gcol, (acc[mi][ni][rr] + bb) * g);
          }
        }
      }
    }
  }
}

extern "C" void kernel_launch(void* const* d_in, const int* in_sizes, int n_in,
                              void* d_out, int out_size, void* d_ws, size_t ws_size,
                              hipStream_t stream){
  const float* x   = (const float*)d_in[0];
  const float* gw  = (const float*)d_in[1];
  const float* w1  = (const float*)d_in[2];
  const float* b1  = (const float*)d_in[3];
  const float* w2  = (const float*)d_in[4];
  const float* b2  = (const float*)d_in[5];
  float* out = (float*)d_out;
  char* ws = (char*)d_ws;
  unsigned short* Wt = (unsigned short*)(ws + (size_t)WS_WT);

  hipMemsetAsync(ws, 0, 512, stream);                                   // counters + jobs
  hipMemsetAsync(out, 0, (size_t)NTOK * D_MODEL * sizeof(float), stream);

  moe_gate_kernel<<<NTOK/4, 256, 0, stream>>>(x, gw, (int*)(ws+WS_CNT),
                                              (int*)(ws+WS_TI), (float*)(ws+WS_TW));
  moe_prefix_kernel<<<1, 64, 0, stream>>>((const int*)(ws+WS_CNT), (int*)(ws+WS_OFF),
                                          (int*)(ws+WS_JOBS));
  moe_assign_kernel<<<NTOK, 256, 0, stream>>>(x, (const int*)(ws+WS_TI),
                                              (const float*)(ws+WS_TW), (const int*)(ws+WS_OFF),
                                              (int*)(ws+WS_CNT2), (int*)(ws+WS_TOK),
                                              (float*)(ws+WS_GWT),
                                              (unsigned short*)(ws + (size_t)WS_XG));
  // W1 (E,1024,4096) f32 -> Wt (E,4096,1024) bf16 ; then GEMM1
  transpose_bf16_kernel<<<dim3(D_FF/64, D_MODEL/64, NEXP), 256, 0, stream>>>(w1, Wt, D_MODEL, D_FF);
  moe_gemm_kernel<1><<<dim3(D_FF/256, MAXJOBS), 512, 0, stream>>>(ws, Wt, b1, out);
  // W2 (E,4096,1024) f32 -> Wt (E,1024,4096) bf16 ; then GEMM2 (K split 2-way)
  transpose_bf16_kernel<<<dim3(D_MODEL/64, D_FF/64, NEXP), 256, 0, stream>>>(w2, Wt, D_FF, D_MODEL);
  moe_gemm_kernel<2><<<dim3((D_MODEL/256)*2, MAXJOBS), 512, 0, stream>>>(ws, Wt, b2, out);
}

// Round 14
// 568.202 us; speedup vs baseline: 1.1257x; 1.1257x over previous
//
#include <hip/hip_runtime.h>
#include <hip/hip_bf16.h>
#include <math.h>

#define D_MODEL 1024
#define D_FF    4096
#define NEXP    8
#define NTOK    4096
#define NROUTED 8192
#define MAXJOBS 40

typedef __attribute__((ext_vector_type(8))) short bf16x8;
typedef __attribute__((ext_vector_type(4))) float f32x4;
typedef __attribute__((ext_vector_type(4))) unsigned short us4;

// ---- workspace byte offsets ----
#define WS_CNT   0                         // int[8]
#define WS_CNT2  64                        // int[8]
#define WS_OFF   128                       // int[9]
#define WS_JOBS  192                       // int[1+MAXJOBS]
#define WS_TI    512                       // int[NTOK*2]
#define WS_TW    (WS_TI + NTOK*2*4)        // float[NTOK*2]
#define WS_TOK   (WS_TW + NTOK*2*4)        // int[NROUTED]
#define WS_GWT   (WS_TOK + NROUTED*4)      // float[NROUTED]
#define WS_XG    (((WS_GWT + NROUTED*4) + 255) & ~255)       // bf16[NROUTED][1024]  (16 MB)
#define WS_H     (WS_XG + (size_t)NROUTED*D_MODEL*2)         // bf16[NROUTED][4096]  (64 MB)
#define WS_WT    (WS_H + (size_t)NROUTED*D_FF*2)             // bf16[E][F][K]        (64 MB)
#define WS_WT2   (WS_WT + (size_t)NEXP*D_FF*D_MODEL*2)       // bf16[E][F][K] #2     (64 MB)
#define WS_END   (WS_WT2 + (size_t)NEXP*D_FF*D_MODEL*2)      // ~208 MB (big path)

__device__ __forceinline__ unsigned short f2bf(float f){
  union { float f; unsigned u; } a; a.f = f;
  unsigned u = a.u;
  u = u + 0x7FFF + ((u >> 16) & 1);   // RNE
  return (unsigned short)(u >> 16);
}

__device__ __forceinline__ void gload_lds16(const void* g, void* l){
  __builtin_amdgcn_global_load_lds((const __attribute__((address_space(1))) void*)g,
                                   (__attribute__((address_space(3))) void*)l, 16, 0, 0);
}

// ---------------- gating ----------------
__global__ void moe_gate_kernel(const float* __restrict__ x, const float* __restrict__ gw,
                                int* cnt, int* __restrict__ ti, float* __restrict__ tw){
  int n = blockIdx.x*4 + (threadIdx.x >> 6);
  int lane = threadIdx.x & 63;
  const float* xr = x + (size_t)n * D_MODEL;
  float acc[NEXP];
  #pragma unroll
  for (int e=0;e<NEXP;e++) acc[e] = 0.f;
  for (int d=lane; d<D_MODEL; d+=64){
    float xv = xr[d];
    #pragma unroll
    for (int e=0;e<NEXP;e++) acc[e] += xv * gw[d*NEXP + e];
  }
  #pragma unroll
  for (int e=0;e<NEXP;e++){
    #pragma unroll
    for (int o=32;o;o>>=1) acc[e] += __shfl_down(acc[e], o, 64);
  }
  if (lane == 0){
    int i0 = 0; float v0 = acc[0];
    #pragma unroll
    for (int e=1;e<NEXP;e++) if (acc[e] > v0){ v0 = acc[e]; i0 = e; }
    int i1 = -1; float v1 = -1e30f;
    #pragma unroll
    for (int e=0;e<NEXP;e++) if (e != i0 && acc[e] > v1){ v1 = acc[e]; i1 = e; }
    float p = expf(v1 - v0);
    float inv = 1.f / (1.f + p);
    ti[n*2] = i0; ti[n*2+1] = i1;
    tw[n*2] = inv; tw[n*2+1] = p * inv;
    atomicAdd(&cnt[i0], 1); atomicAdd(&cnt[i1], 1);
  }
}

// prefix sums + job list (job = one 256-row stripe of one expert)
__global__ void moe_prefix_kernel(const int* __restrict__ cnt, int* __restrict__ off,
                                  int* __restrict__ jobs){
  if (threadIdx.x == 0){
    int s = 0;
    for (int e=0;e<NEXP;e++){ off[e] = s; s += cnt[e]; }
    off[NEXP] = s;
    int idx = 0;
    for (int e=0;e<NEXP;e++){
      int ns = (cnt[e] + 255) >> 8;
      for (int q=0;q<ns;q++) jobs[1+idx++] = (e<<16) | q;
    }
    jobs[0] = idx;
  }
}

// ---------------- device bodies for the fused mid kernel ----------------
__device__ __forceinline__ void assign_body(
    int n, const float* __restrict__ x, const int* __restrict__ ti,
    const float* __restrict__ tw, const int* __restrict__ off,
    int* cnt2, int* __restrict__ tok, float* __restrict__ gwt,
    unsigned short* __restrict__ Xg){
  __shared__ int ss[2];
  if (threadIdx.x == 0){
    int i0 = ti[n*2], i1 = ti[n*2+1];
    int s0 = off[i0] + atomicAdd(&cnt2[i0], 1);
    int s1 = off[i1] + atomicAdd(&cnt2[i1], 1);
    tok[s0] = n; tok[s1] = n;
    gwt[s0] = tw[n*2]; gwt[s1] = tw[n*2+1];
    ss[0] = s0; ss[1] = s1;
  }
  __syncthreads();
  int s0 = ss[0], s1 = ss[1];
  int t = threadIdx.x;
  f32x4 v = *(const f32x4*)(x + (size_t)n * D_MODEL + t*4);
  us4 pk = { f2bf(v.x), f2bf(v.y), f2bf(v.z), f2bf(v.w) };
  __builtin_nontemporal_store(pk, (us4*)(Xg + (size_t)s0 * D_MODEL + t*4));
  __builtin_nontemporal_store(pk, (us4*)(Xg + (size_t)s1 * D_MODEL + t*4));
}

// W(E,K,F) f32 -> Wt(E,F,K) bf16, one 64x64 tile per block
__device__ __forceinline__ void transpose_body(
    int idx, const float* __restrict__ W, unsigned short* __restrict__ Wt, int K, int F){
  __shared__ float tile[64][65];
  int fpe = F >> 6, kpe = K >> 6;
  int e = idx / (fpe*kpe), rem = idx % (fpe*kpe);
  int f0 = (rem % fpe) * 64, k0 = (rem / fpe) * 64;
  const float* Wb = W + (size_t)e * K * F;
  unsigned short* Wtb = Wt + (size_t)e * F * K;
  int tid = threadIdx.x;
  #pragma unroll
  for (int i=0;i<4;i++){
    int q = i*256 + tid;
    int r = q >> 4, c4 = (q & 15) * 4;
    f32x4 v = __builtin_nontemporal_load((const f32x4*)(Wb + (size_t)(k0 + r) * F + f0 + c4));
    tile[r][c4] = v.x; tile[r][c4+1] = v.y; tile[r][c4+2] = v.z; tile[r][c4+3] = v.w;
  }
  __syncthreads();
  #pragma unroll
  for (int i=0;i<4;i++){
    int q = i*256 + tid;
    int f = q >> 4, k4 = (q & 15) * 4;
    us4 pk = { f2bf(tile[k4][f]), f2bf(tile[k4+1][f]), f2bf(tile[k4+2][f]), f2bf(tile[k4+3][f]) };
    __builtin_nontemporal_store(pk, (us4*)(Wtb + (size_t)(f0 + f) * K + k0 + k4));
  }
}

// standalone kernels (fallback path)
__global__ void moe_assign_kernel(const float* x, const int* ti, const float* tw,
                                  const int* off, int* cnt2, int* tok, float* gwt,
                                  unsigned short* Xg){
  assign_body(blockIdx.x, x, ti, tw, off, cnt2, tok, gwt, Xg);
}
__global__ __launch_bounds__(256) void transpose_bf16_kernel(
    const float* W, unsigned short* Wt, int K, int F){
  transpose_body(blockIdx.x, W, Wt, K, F);
}

// fused: assign (NTOK) + transpose w1 (8192) + transpose w2 (8192), all independent
__global__ __launch_bounds__(256) void moe_fused_mid_kernel(
    const float* __restrict__ x, const int* __restrict__ ti, const float* __restrict__ tw,
    const int* __restrict__ off, int* cnt2, int* __restrict__ tok, float* __restrict__ gwt,
    unsigned short* __restrict__ Xg,
    const float* __restrict__ w1, unsigned short* __restrict__ Wt1,
    const float* __restrict__ w2, unsigned short* __restrict__ Wt2){
  int b = blockIdx.x;
  if (b < NTOK){
    assign_body(b, x, ti, tw, off, cnt2, tok, gwt, Xg);
  } else if (b < NTOK + 8192){
    transpose_body(b - NTOK, w1, Wt1, D_MODEL, D_FF);
  } else {
    transpose_body(b - NTOK - 8192, w2, Wt2, D_FF, D_MODEL);
  }
}

// ---------------- GEMM: 256x256 tile, BK=32, 16 waves (1024 thr), ring-3 LDS, counted vmcnt ----------------
// (byte-identical to r11 best: 173 us/dispatch)
template<int MODE>
__global__ __launch_bounds__(1024) void moe_gemm_kernel(
    char* __restrict__ wsb, const unsigned short* __restrict__ Bt,
    const float* __restrict__ bias, float* __restrict__ out)
{
  const int* jobs = (const int*)(wsb + WS_JOBS);
  if ((int)blockIdx.y >= jobs[0]) return;
  const int jb = jobs[1 + blockIdx.y];
  const int e = jb >> 16;
  const int row0 = (jb & 0xffff) << 8;

  const int* off = (const int*)(wsb + WS_OFF);
  const int n0 = off[e];
  const int ne = off[e+1] - n0;

  constexpr int K  = (MODE==1) ? D_MODEL : D_FF;
  constexpr int NT = (MODE==1) ? 32 : 64;         // BK=32 K-steps
  const int bx     = (MODE==1) ? blockIdx.x : (blockIdx.x & 3);
  const int kchunk = (MODE==1) ? 0 : (blockIdx.x >> 2);
  const int n_off  = bx * 256;
  const size_t kcb = (size_t)kchunk * 4096;       // byte offset of 2048-wide K-chunk

  const unsigned short* Ag = (const unsigned short*)(wsb + (MODE==1 ? (size_t)WS_XG : (size_t)WS_H));

  __shared__ __align__(16) char lds[3*32768];     // ring: [slot][ A 16KB | B 16KB ]

  const int tid = threadIdx.x, lane = tid & 63, w = tid >> 6;
  const int wr = w >> 2, wc = w & 3;              // 4x4 wave grid; wave tile 64x64

  const int rA   = w*16 + (lane >> 2);            // 0..255
  const int qs   = ((lane & 3) ^ ((rA >> 1) & 3)) << 4;   // pre-swizzled source chunk
  int grA = row0 + rA; if (grA >= ne) grA = ne - 1;
  const char* aSrc = (const char*)(Ag + (size_t)(n0 + grA) * K) + kcb + qs;
  const char* bSrc = (const char*)(Bt + (size_t)e * D_FF * D_MODEL + (size_t)(n_off + rA) * K) + kcb + qs;
  const int dA = w*1024, dB = 16384 + w*1024;     // wave-uniform LDS dests

  const int q0 = lane >> 4;
  int aoff[4], boff[4];
  #pragma unroll
  for (int mi=0; mi<4; mi++){
    int row = wr*64 + mi*16 + (lane & 15);
    aoff[mi] = row*64 + ((q0 ^ ((row>>1)&3)) << 4);
  }
  #pragma unroll
  for (int ni=0; ni<4; ni++){
    int col = wc*64 + ni*16 + (lane & 15);
    boff[ni] = 16384 + col*64 + ((q0 ^ ((col>>1)&3)) << 4);
  }

  f32x4 acc[4][4];
  #pragma unroll
  for (int i=0;i<4;i++)
    #pragma unroll
    for (int j=0;j<4;j++) acc[i][j] = (f32x4){0.f,0.f,0.f,0.f};

  #define STAGE(tt, ss) { \
    gload_lds16(aSrc + (size_t)(tt)*64, lds + (ss)*32768 + dA); \
    gload_lds16(bSrc + (size_t)(tt)*64, lds + (ss)*32768 + dB); }

  STAGE(0, 0);
  STAGE(1, 1);

  for (int t = 0; t < NT; ++t){
    if (t < NT-1) asm volatile("s_waitcnt vmcnt(2)" ::: "memory");
    else          asm volatile("s_waitcnt vmcnt(0)" ::: "memory");
    __builtin_amdgcn_s_barrier();
    __builtin_amdgcn_sched_barrier(0);

    if (t + 2 < NT) STAGE(t + 2, (t + 2) % 3);

    const char* base = lds + (t % 3) * 32768;
    bf16x8 a[4], b[4];
    #pragma unroll
    for (int mi=0; mi<4; mi++) a[mi] = *(const bf16x8*)(base + aoff[mi]);
    #pragma unroll
    for (int ni=0; ni<4; ni++) b[ni] = *(const bf16x8*)(base + boff[ni]);

    asm volatile("s_waitcnt lgkmcnt(0)" ::: "memory");
    __builtin_amdgcn_sched_barrier(0);
    __builtin_amdgcn_s_setprio(1);
    #pragma unroll
    for (int ni=0; ni<4; ni++)
      #pragma unroll
      for (int mi=0; mi<4; mi++)
        acc[mi][ni] = __builtin_amdgcn_mfma_f32_16x16x32_bf16(a[mi], b[ni], acc[mi][ni], 0, 0, 0);
    __builtin_amdgcn_s_setprio(0);
    __builtin_amdgcn_sched_barrier(0);
  }
  #undef STAGE

  if (MODE == 1){
    const float* b1 = bias + (size_t)e * D_FF;
    unsigned short* H = (unsigned short*)(wsb + (size_t)WS_H);
    #pragma unroll
    for (int mi=0; mi<4; mi++){
      int rbase = wr*64 + mi*16 + ((lane>>4)<<2);
      #pragma unroll
      for (int rr=0;rr<4;rr++){
        int lrow = rbase + rr;
        if (row0 + lrow < ne){
          size_t hb = (size_t)(n0 + row0 + lrow) * D_FF;
          #pragma unroll
          for (int ni=0; ni<4; ni++){
            int gcol = n_off + wc*64 + ni*16 + (lane&15);
            float v = acc[mi][ni][rr] + b1[gcol];
            v = 0.5f * v * (1.f + erff(v * 0.70710678118654752f));
            __builtin_nontemporal_store(f2bf(v), H + hb + gcol);
          }
        }
      }
    }
  } else {
    const float* b2 = bias + (size_t)e * D_MODEL;
    const int* tok = (const int*)(wsb + WS_TOK);
    const float* gwt = (const float*)(wsb + WS_GWT);
    #pragma unroll
    for (int mi=0; mi<4; mi++){
      int rbase = wr*64 + mi*16 + ((lane>>4)<<2);
      #pragma unroll
      for (int rr=0;rr<4;rr++){
        int lrow = rbase + rr;
        if (row0 + lrow < ne){
          int slot = n0 + row0 + lrow;
          int tk = tok[slot];
          float g = gwt[slot];
          float* orow = out + (size_t)tk * D_MODEL;
          #pragma unroll
          for (int ni=0; ni<4; ni++){
            int gcol = n_off + wc*64 + ni*16 + (lane&15);
            float bb = (kchunk == 0) ? b2[gcol] : 0.f;
            atomicAdd(orow + gcol, (acc[mi][ni][rr] + bb) * g);
          }
        }
      }
    }
  }
}

extern "C" void kernel_launch(void* const* d_in, const int* in_sizes, int n_in,
                              void* d_out, int out_size, void* d_ws, size_t ws_size,
                              hipStream_t stream){
  const float* x   = (const float*)d_in[0];
  const float* gw  = (const float*)d_in[1];
  const float* w1  = (const float*)d_in[2];
  const float* b1  = (const float*)d_in[3];
  const float* w2  = (const float*)d_in[4];
  const float* b2  = (const float*)d_in[5];
  float* out = (float*)d_out;
  char* ws = (char*)d_ws;
  unsigned short* Wt1 = (unsigned short*)(ws + (size_t)WS_WT);
  unsigned short* Wt2 = (unsigned short*)(ws + (size_t)WS_WT2);

  hipMemsetAsync(ws, 0, 512, stream);                                   // counters + jobs
  hipMemsetAsync(out, 0, (size_t)NTOK * D_MODEL * sizeof(float), stream);

  moe_gate_kernel<<<NTOK/4, 256, 0, stream>>>(x, gw, (int*)(ws+WS_CNT),
                                              (int*)(ws+WS_TI), (float*)(ws+WS_TW));
  moe_prefix_kernel<<<1, 64, 0, stream>>>((const int*)(ws+WS_CNT), (int*)(ws+WS_OFF),
                                          (int*)(ws+WS_JOBS));

  if (ws_size >= (size_t)WS_END){
    // big path: assign + both transposes fused (independent streams share BW)
    moe_fused_mid_kernel<<<NTOK + 16384, 256, 0, stream>>>(
        x, (const int*)(ws+WS_TI), (const float*)(ws+WS_TW), (const int*)(ws+WS_OFF),
        (int*)(ws+WS_CNT2), (int*)(ws+WS_TOK), (float*)(ws+WS_GWT),
        (unsigned short*)(ws + (size_t)WS_XG), w1, Wt1, w2, Wt2);
    moe_gemm_kernel<1><<<dim3(D_FF/256, MAXJOBS), 1024, 0, stream>>>(ws, Wt1, b1, out);
    moe_gemm_kernel<2><<<dim3((D_MODEL/256)*2, MAXJOBS), 1024, 0, stream>>>(ws, Wt2, b2, out);
  } else {
    // fallback: r11 sequential (Wt2 aliases Wt1 region)
    moe_assign_kernel<<<NTOK, 256, 0, stream>>>(x, (const int*)(ws+WS_TI),
                                                (const float*)(ws+WS_TW), (const int*)(ws+WS_OFF),
                                                (int*)(ws+WS_CNT2), (int*)(ws+WS_TOK),
                                                (float*)(ws+WS_GWT),
                                                (unsigned short*)(ws + (size_t)WS_XG));
    transpose_bf16_kernel<<<8192, 256, 0, stream>>>(w1, Wt1, D_MODEL, D_FF);
    moe_gemm_kernel<1><<<dim3(D_FF/256, MAXJOBS), 1024, 0, stream>>>(ws, Wt1, b1, out);
    transpose_bf16_kernel<<<8192, 256, 0, stream>>>(w2, Wt1, D_FF, D_MODEL);
    moe_gemm_kernel<2><<<dim3((D_MODEL/256)*2, MAXJOBS), 1024, 0, stream>>>(ws, Wt1, b2, out);
  }
}

// Round 15
// 540.719 us; speedup vs baseline: 1.1830x; 1.0508x over previous
//
#include <hip/hip_runtime.h>
#include <hip/hip_bf16.h>
#include <math.h>

#define D_MODEL 1024
#define D_FF    4096
#define NEXP    8
#define NTOK    4096
#define NROUTED 8192
#define MAXJOBS 40

typedef __attribute__((ext_vector_type(8))) short bf16x8;
typedef __attribute__((ext_vector_type(4))) float f32x4;
typedef __attribute__((ext_vector_type(4))) unsigned short us4;

// ---- workspace byte offsets ----
#define WS_CNT   0                         // int[8]
#define WS_CNT2  64                        // int[8]
#define WS_OFF   128                       // int[9]
#define WS_JOBS  192                       // int[1+MAXJOBS]
#define WS_TI    512                       // int[NTOK*2]
#define WS_TW    (WS_TI + NTOK*2*4)        // float[NTOK*2]
#define WS_TOK   (WS_TW + NTOK*2*4)        // int[NROUTED]
#define WS_GWT   (WS_TOK + NROUTED*4)      // float[NROUTED]
#define WS_XG    (((WS_GWT + NROUTED*4) + 255) & ~255)       // bf16[NROUTED][1024]  (16 MB)
#define WS_H     (WS_XG + (size_t)NROUTED*D_MODEL*2)         // bf16[NROUTED][4096]  (64 MB)
#define WS_WT    (WS_H + (size_t)NROUTED*D_FF*2)             // bf16[E][F][K]        (64 MB)
#define WS_WT2   (WS_WT + (size_t)NEXP*D_FF*D_MODEL*2)       // bf16[E][F][K] #2     (64 MB)
#define WS_END   (WS_WT2 + (size_t)NEXP*D_FF*D_MODEL*2)      // ~208 MB (big path)

__device__ __forceinline__ unsigned short f2bf(float f){
  union { float f; unsigned u; } a; a.f = f;
  unsigned u = a.u;
  u = u + 0x7FFF + ((u >> 16) & 1);   // RNE
  return (unsigned short)(u >> 16);
}

__device__ __forceinline__ void gload_lds16(const void* g, void* l){
  __builtin_amdgcn_global_load_lds((const __attribute__((address_space(1))) void*)g,
                                   (__attribute__((address_space(3))) void*)l, 16, 0, 0);
}

// ---------------- gating ----------------
__global__ void moe_gate_kernel(const float* __restrict__ x, const float* __restrict__ gw,
                                int* cnt, int* __restrict__ ti, float* __restrict__ tw){
  int n = blockIdx.x*4 + (threadIdx.x >> 6);
  int lane = threadIdx.x & 63;
  const float* xr = x + (size_t)n * D_MODEL;
  float acc[NEXP];
  #pragma unroll
  for (int e=0;e<NEXP;e++) acc[e] = 0.f;
  for (int d=lane; d<D_MODEL; d+=64){
    float xv = xr[d];
    #pragma unroll
    for (int e=0;e<NEXP;e++) acc[e] += xv * gw[d*NEXP + e];
  }
  #pragma unroll
  for (int e=0;e<NEXP;e++){
    #pragma unroll
    for (int o=32;o;o>>=1) acc[e] += __shfl_down(acc[e], o, 64);
  }
  if (lane == 0){
    int i0 = 0; float v0 = acc[0];
    #pragma unroll
    for (int e=1;e<NEXP;e++) if (acc[e] > v0){ v0 = acc[e]; i0 = e; }
    int i1 = -1; float v1 = -1e30f;
    #pragma unroll
    for (int e=0;e<NEXP;e++) if (e != i0 && acc[e] > v1){ v1 = acc[e]; i1 = e; }
    float p = expf(v1 - v0);
    float inv = 1.f / (1.f + p);
    ti[n*2] = i0; ti[n*2+1] = i1;
    tw[n*2] = inv; tw[n*2+1] = p * inv;
    atomicAdd(&cnt[i0], 1); atomicAdd(&cnt[i1], 1);
  }
}

// prefix sums + job list (job = one 256-row stripe of one expert)
__global__ void moe_prefix_kernel(const int* __restrict__ cnt, int* __restrict__ off,
                                  int* __restrict__ jobs){
  if (threadIdx.x == 0){
    int s = 0;
    for (int e=0;e<NEXP;e++){ off[e] = s; s += cnt[e]; }
    off[NEXP] = s;
    int idx = 0;
    for (int e=0;e<NEXP;e++){
      int ns = (cnt[e] + 255) >> 8;
      for (int q=0;q<ns;q++) jobs[1+idx++] = (e<<16) | q;
    }
    jobs[0] = idx;
  }
}

// ---------------- device bodies ----------------
__device__ __forceinline__ void assign_body(
    int n, const float* __restrict__ x, const int* __restrict__ ti,
    const float* __restrict__ tw, const int* __restrict__ off,
    int* cnt2, int* __restrict__ tok, float* __restrict__ gwt,
    unsigned short* __restrict__ Xg){
  __shared__ int ss[2];
  if (threadIdx.x == 0){
    int i0 = ti[n*2], i1 = ti[n*2+1];
    int s0 = off[i0] + atomicAdd(&cnt2[i0], 1);
    int s1 = off[i1] + atomicAdd(&cnt2[i1], 1);
    tok[s0] = n; tok[s1] = n;
    gwt[s0] = tw[n*2]; gwt[s1] = tw[n*2+1];
    ss[0] = s0; ss[1] = s1;
  }
  __syncthreads();
  int s0 = ss[0], s1 = ss[1];
  int t = threadIdx.x;
  f32x4 v = *(const f32x4*)(x + (size_t)n * D_MODEL + t*4);
  us4 pk = { f2bf(v.x), f2bf(v.y), f2bf(v.z), f2bf(v.w) };
  __builtin_nontemporal_store(pk, (us4*)(Xg + (size_t)s0 * D_MODEL + t*4));
  __builtin_nontemporal_store(pk, (us4*)(Xg + (size_t)s1 * D_MODEL + t*4));
}

// W(E,K,F) f32 -> Wt(E,F,K) bf16; one 64x64 tile; 256-thread group with group-local tid
__device__ __forceinline__ void transpose_tile(
    int idx, int gtid, float (*tile)[65],
    const float* __restrict__ W, unsigned short* __restrict__ Wt, int K, int F){
  int fpe = F >> 6, kpe = K >> 6;
  int e = idx / (fpe*kpe), rem = idx % (fpe*kpe);
  int f0 = (rem % fpe) * 64, k0 = (rem / fpe) * 64;
  const float* Wb = W + (size_t)e * K * F;
  unsigned short* Wtb = Wt + (size_t)e * F * K;
  #pragma unroll
  for (int i=0;i<4;i++){
    int q = i*256 + gtid;
    int r = q >> 4, c4 = (q & 15) * 4;
    f32x4 v = __builtin_nontemporal_load((const f32x4*)(Wb + (size_t)(k0 + r) * F + f0 + c4));
    tile[r][c4] = v.x; tile[r][c4+1] = v.y; tile[r][c4+2] = v.z; tile[r][c4+3] = v.w;
  }
  __syncthreads();
  #pragma unroll
  for (int i=0;i<4;i++){
    int q = i*256 + gtid;
    int f = q >> 4, k4 = (q & 15) * 4;
    us4 pk = { f2bf(tile[k4][f]), f2bf(tile[k4+1][f]), f2bf(tile[k4+2][f]), f2bf(tile[k4+3][f]) };
    __builtin_nontemporal_store(pk, (us4*)(Wtb + (size_t)(f0 + f) * K + k0 + k4));
  }
}

// standalone transpose (fallback path)
__global__ __launch_bounds__(256) void transpose_bf16_kernel(
    const float* W, unsigned short* Wt, int K, int F){
  __shared__ float tile[64][65];
  transpose_tile(blockIdx.x, threadIdx.x, tile, W, Wt, K, F);
}

// fusedA: assign (NTOK blocks) + transpose w1 (8192 blocks) — fits 144 MB path
__global__ __launch_bounds__(256) void moe_fusedA_kernel(
    const float* __restrict__ x, const int* __restrict__ ti, const float* __restrict__ tw,
    const int* __restrict__ off, int* cnt2, int* __restrict__ tok, float* __restrict__ gwt,
    unsigned short* __restrict__ Xg,
    const float* __restrict__ w1, unsigned short* __restrict__ Wt1){
  int b = blockIdx.x;
  if (b < NTOK){
    assign_body(b, x, ti, tw, off, cnt2, tok, gwt, Xg);
  } else {
    __shared__ float tile[64][65];
    transpose_tile(b - NTOK, threadIdx.x, tile, w1, Wt1, D_MODEL, D_FF);
  }
}

// ---------------- GEMM: 256x256 tile, BK=32, 16 waves, ring-3 LDS, counted vmcnt ----------------
// MODE 1 additionally carries transpose-w2 blocks at blockIdx.y >= MAXJOBS (big path):
// each such block = 4 x 64x64 transpose tiles (4 x 256-thread groups), backfilling CU bubbles.
template<int MODE>
__global__ __launch_bounds__(1024) void moe_gemm_kernel(
    char* __restrict__ wsb, const unsigned short* __restrict__ Bt,
    const float* __restrict__ bias, float* __restrict__ out,
    const float* __restrict__ w2src, unsigned short* __restrict__ Wt2)
{
  __shared__ __align__(16) char lds[3*32768];     // GEMM: ring-3; transpose: 4x64x65 f32 (66.6KB)

  if (MODE == 1 && (int)blockIdx.y >= MAXJOBS){
    int slot = ((int)blockIdx.y - MAXJOBS) * (int)gridDim.x + (int)blockIdx.x;
    int g = threadIdx.x >> 8, gtid = threadIdx.x & 255;
    float (*tiles)[64][65] = (float(*)[64][65])lds;
    transpose_tile(slot*4 + g, gtid, tiles[g], w2src, Wt2, D_FF, D_MODEL);
    return;
  }

  const int* jobs = (const int*)(wsb + WS_JOBS);
  if ((int)blockIdx.y >= jobs[0]) return;
  const int jb = jobs[1 + blockIdx.y];
  const int e = jb >> 16;
  const int row0 = (jb & 0xffff) << 8;

  const int* off = (const int*)(wsb + WS_OFF);
  const int n0 = off[e];
  const int ne = off[e+1] - n0;

  constexpr int K  = (MODE==1) ? D_MODEL : D_FF;
  constexpr int NT = (MODE==1) ? 32 : 64;         // BK=32 K-steps
  const int bx     = (MODE==1) ? blockIdx.x : (blockIdx.x & 3);
  const int kchunk = (MODE==1) ? 0 : (blockIdx.x >> 2);
  const int n_off  = bx * 256;
  const size_t kcb = (size_t)kchunk * 4096;       // byte offset of 2048-wide K-chunk

  const unsigned short* Ag = (const unsigned short*)(wsb + (MODE==1 ? (size_t)WS_XG : (size_t)WS_H));

  const int tid = threadIdx.x, lane = tid & 63, w = tid >> 6;
  const int wr = w >> 2, wc = w & 3;              // 4x4 wave grid; wave tile 64x64

  const int rA   = w*16 + (lane >> 2);            // 0..255
  const int qs   = ((lane & 3) ^ ((rA >> 1) & 3)) << 4;   // pre-swizzled source chunk
  int grA = row0 + rA; if (grA >= ne) grA = ne - 1;
  const char* aSrc = (const char*)(Ag + (size_t)(n0 + grA) * K) + kcb + qs;
  const char* bSrc = (const char*)(Bt + (size_t)e * D_FF * D_MODEL + (size_t)(n_off + rA) * K) + kcb + qs;
  const int dA = w*1024, dB = 16384 + w*1024;     // wave-uniform LDS dests

  const int q0 = lane >> 4;
  int aoff[4], boff[4];
  #pragma unroll
  for (int mi=0; mi<4; mi++){
    int row = wr*64 + mi*16 + (lane & 15);
    aoff[mi] = row*64 + ((q0 ^ ((row>>1)&3)) << 4);
  }
  #pragma unroll
  for (int ni=0; ni<4; ni++){
    int col = wc*64 + ni*16 + (lane & 15);
    boff[ni] = 16384 + col*64 + ((q0 ^ ((col>>1)&3)) << 4);
  }

  f32x4 acc[4][4];
  #pragma unroll
  for (int i=0;i<4;i++)
    #pragma unroll
    for (int j=0;j<4;j++) acc[i][j] = (f32x4){0.f,0.f,0.f,0.f};

  #define STAGE(tt, ss) { \
    gload_lds16(aSrc + (size_t)(tt)*64, lds + (ss)*32768 + dA); \
    gload_lds16(bSrc + (size_t)(tt)*64, lds + (ss)*32768 + dB); }

  STAGE(0, 0);
  STAGE(1, 1);

  for (int t = 0; t < NT; ++t){
    if (t < NT-1) asm volatile("s_waitcnt vmcnt(2)" ::: "memory");
    else          asm volatile("s_waitcnt vmcnt(0)" ::: "memory");
    __builtin_amdgcn_s_barrier();
    __builtin_amdgcn_sched_barrier(0);

    if (t + 2 < NT) STAGE(t + 2, (t + 2) % 3);

    const char* base = lds + (t % 3) * 32768;
    bf16x8 a[4], b[4];
    #pragma unroll
    for (int mi=0; mi<4; mi++) a[mi] = *(const bf16x8*)(base + aoff[mi]);
    #pragma unroll
    for (int ni=0; ni<4; ni++) b[ni] = *(const bf16x8*)(base + boff[ni]);

    asm volatile("s_waitcnt lgkmcnt(0)" ::: "memory");
    __builtin_amdgcn_sched_barrier(0);
    __builtin_amdgcn_s_setprio(1);
    #pragma unroll
    for (int ni=0; ni<4; ni++)
      #pragma unroll
      for (int mi=0; mi<4; mi++)
        acc[mi][ni] = __builtin_amdgcn_mfma_f32_16x16x32_bf16(a[mi], b[ni], acc[mi][ni], 0, 0, 0);
    __builtin_amdgcn_s_setprio(0);
    __builtin_amdgcn_sched_barrier(0);
  }
  #undef STAGE

  if (MODE == 1){
    const float* b1 = bias + (size_t)e * D_FF;
    unsigned short* H = (unsigned short*)(wsb + (size_t)WS_H);
    #pragma unroll
    for (int mi=0; mi<4; mi++){
      int rbase = wr*64 + mi*16 + ((lane>>4)<<2);
      #pragma unroll
      for (int rr=0;rr<4;rr++){
        int lrow = rbase + rr;
        if (row0 + lrow < ne){
          size_t hb = (size_t)(n0 + row0 + lrow) * D_FF;
          #pragma unroll
          for (int ni=0; ni<4; ni++){
            int gcol = n_off + wc*64 + ni*16 + (lane&15);
            float v = acc[mi][ni][rr] + b1[gcol];
            v = 0.5f * v * (1.f + erff(v * 0.70710678118654752f));
            __builtin_nontemporal_store(f2bf(v), H + hb + gcol);
          }
        }
      }
    }
  } else {
    const float* b2 = bias + (size_t)e * D_MODEL;
    const int* tok = (const int*)(wsb + WS_TOK);
    const float* gwt = (const float*)(wsb + WS_GWT);
    #pragma unroll
    for (int mi=0; mi<4; mi++){
      int rbase = wr*64 + mi*16 + ((lane>>4)<<2);
      #pragma unroll
      for (int rr=0;rr<4;rr++){
        int lrow = rbase + rr;
        if (row0 + lrow < ne){
          int slot = n0 + row0 + lrow;
          int tk = tok[slot];
          float g = gwt[slot];
          float* orow = out + (size_t)tk * D_MODEL;
          #pragma unroll
          for (int ni=0; ni<4; ni++){
            int gcol = n_off + wc*64 + ni*16 + (lane&15);
            float bb = (kchunk == 0) ? b2[gcol] : 0.f;
            atomicAdd(orow + gcol, (acc[mi][ni][rr] + bb) * g);
          }
        }
      }
    }
  }
}

extern "C" void kernel_launch(void* const* d_in, const int* in_sizes, int n_in,
                              void* d_out, int out_size, void* d_ws, size_t ws_size,
                              hipStream_t stream){
  const float* x   = (const float*)d_in[0];
  const float* gw  = (const float*)d_in[1];
  const float* w1  = (const float*)d_in[2];
  const float* b1  = (const float*)d_in[3];
  const float* w2  = (const float*)d_in[4];
  const float* b2  = (const float*)d_in[5];
  float* out = (float*)d_out;
  char* ws = (char*)d_ws;
  unsigned short* Wt1 = (unsigned short*)(ws + (size_t)WS_WT);
  unsigned short* Wt2 = (unsigned short*)(ws + (size_t)WS_WT2);

  hipMemsetAsync(ws, 0, 512, stream);                                   // counters + jobs
  hipMemsetAsync(out, 0, (size_t)NTOK * D_MODEL * sizeof(float), stream);

  moe_gate_kernel<<<NTOK/4, 256, 0, stream>>>(x, gw, (int*)(ws+WS_CNT),
                                              (int*)(ws+WS_TI), (float*)(ws+WS_TW));
  moe_prefix_kernel<<<1, 64, 0, stream>>>((const int*)(ws+WS_CNT), (int*)(ws+WS_OFF),
                                          (int*)(ws+WS_JOBS));
  // assign + transpose-w1 fused (both paths)
  moe_fusedA_kernel<<<NTOK + 8192, 256, 0, stream>>>(
      x, (const int*)(ws+WS_TI), (const float*)(ws+WS_TW), (const int*)(ws+WS_OFF),
      (int*)(ws+WS_CNT2), (int*)(ws+WS_TOK), (float*)(ws+WS_GWT),
      (unsigned short*)(ws + (size_t)WS_XG), w1, Wt1);

  if (ws_size >= (size_t)WS_END){
    // big path: transpose-w2 slipstreams inside GEMM1's grid (extra y-rows)
    moe_gemm_kernel<1><<<dim3(D_FF/256, MAXJOBS + 128), 1024, 0, stream>>>(ws, Wt1, b1, out, w2, Wt2);
    moe_gemm_kernel<2><<<dim3((D_MODEL/256)*2, MAXJOBS), 1024, 0, stream>>>(ws, Wt2, b2, out, nullptr, nullptr);
  } else {
    // fallback (ws < 208 MB): serial transpose-w2 into Wt1 region after GEMM1
    moe_gemm_kernel<1><<<dim3(D_FF/256, MAXJOBS), 1024, 0, stream>>>(ws, Wt1, b1, out, nullptr, nullptr);
    transpose_bf16_kernel<<<8192, 256, 0, stream>>>(w2, Wt1, D_FF, D_MODEL);
    moe_gemm_kernel<2><<<dim3((D_MODEL/256)*2, MAXJOBS), 1024, 0, stream>>>(ws, Wt1, b2, out, nullptr, nullptr);
  }
}